// Round 1
// 203.274 us; speedup vs baseline: 1.3148x; 1.3148x over previous
//
#include <hip/hip_runtime.h>

#define NN 10000
#define EE 320000
#define HH 256
#define BKT 192   // per-row bucket capacity (raw deg ~Poisson(32), max ~65; matches old dedup cap)

typedef __attribute__((ext_vector_type(8))) short bf16x8;
typedef __attribute__((ext_vector_type(4))) float f32x4;

__device__ float bf2f(unsigned int v) {
    return __uint_as_float(v << 16);
}
__device__ unsigned short f2bf(float f) {
    unsigned int i = __float_as_uint(f);
    return (unsigned short)((i + 0x7fffu + ((i >> 16) & 1u)) >> 16);
}
// ---- software e4m3 codec (self-consistent; exact for normals, RNE) ----
__device__ unsigned int fp8e(float f) {
    float a = fabsf(f);
    a = fminf(a, 448.0f);
    unsigned int bits = __float_as_uint(a * __uint_as_float(0x03800000u)); // * 2^-120
    bits = bits + 0x7ffffu + ((bits >> 20) & 1u);
    unsigned int r = bits >> 20;
    if (r > 0x7eu) r = 0x7eu;
    return r | ((__float_as_uint(f) >> 24) & 0x80u);
}
__device__ float fp8d(unsigned int b) {
    float mag = __uint_as_float((b & 0x7fu) << 20) * __uint_as_float(0x7B800000u); // * 2^120
    return __uint_as_float(((b & 0x80u) << 24) | __float_as_uint(mag));
}
__device__ unsigned int pk2(unsigned short a, unsigned short b) {
    return (unsigned int)a | ((unsigned int)b << 16);
}

__device__ int eload(const void* ei, int is64, int idx) {
    if (is64) return (int)(((const long long*)ei)[idx]);
    return ((const int*)ei)[idx];
}

// ---- 1. init: zero slotcnt/deg_c everywhere; block 0 also detects dtypes.
//  flags[0]: edge_index is int64. flags[1]: floats are f32.
__global__ void k_init(const unsigned int* xu, const unsigned int* eu, int* flags,
                       int* slotcnt, int* deg_c) {
    int b = blockIdx.x, t = threadIdx.x;
    int i = b * 256 + t;
    if (i < NN) { slotcnt[i] = 0; deg_c[i] = 0; }
    if (b != 0) return;
    __shared__ int odd_nz;
    __shared__ int plaus;
    if (t == 0) { odd_nz = 0; plaus = 0; }
    __syncthreads();
    if (t < 64) {
        for (int k = t; k < 256; k += 64) {
            if (eu[2 * k + 1] != 0) atomicOr(&odd_nz, 1);
        }
        unsigned int lo = xu[t] & 0xffffu;
        unsigned int ex = (lo >> 7) & 0xffu;
        if (lo == 0u || (ex >= 90u && ex <= 150u)) atomicAdd(&plaus, 1);
    }
    __syncthreads();
    if (t == 0) {
        flags[0] = odd_nz ? 0 : 1;
        flags[1] = (plaus >= 56) ? 0 : 1;
    }
}

// ---- 2. merged: blocks [0,64) swizzle weights; [64,1314) single-pass edge
//  scatter into fixed-stride buckets (replaces count+scan+fill).
__global__ void k_prep_scatter(const void* W1, const void* W2, const void* ei,
                               const int* flags, unsigned short* W1sw,
                               unsigned short* W2sw, int* slotcnt,
                               unsigned short* bucket) {
    int b = blockIdx.x;
    if (b >= 64) {
        int e = (b - 64) * 256 + threadIdx.x;   // exactly EE threads
        int is64 = flags[0];
        int r = eload(ei, is64, e);
        int c = eload(ei, is64, EE + e);
        if (r < 0 || r >= NN || c < 0 || c >= NN) return;
        int slot = atomicAdd(&slotcnt[r], 1);
        if (slot < BKT) bucket[(size_t)r * BKT + slot] = (unsigned short)c;
        return;
    }
    const void* W = (b < 32) ? W1 : W2;
    unsigned short* O = (b < 32) ? W1sw : W2sw;
    int g = ((b < 32) ? b : b - 32) * 256 + threadIdx.x;   // 8192 groups of 8
    int lane = g & 63;
    int n = (g >> 6) & 15;
    int ks = g >> 10;
    int coln = n * 16 + (lane & 15);
    int krow = ks * 32 + ((lane >> 4) & 3) * 8;
    unsigned short v[8];
    if (flags[1]) {
        const float* Wf = (const float*)W;
        #pragma unroll
        for (int j = 0; j < 8; j++) v[j] = f2bf(Wf[(size_t)(krow + j) * HH + coln]);
    } else {
        const unsigned short* Wh = (const unsigned short*)W;
        #pragma unroll
        for (int j = 0; j < 8; j++) v[j] = Wh[(size_t)(krow + j) * HH + coln];
    }
    uint4 p;
    p.x = pk2(v[0], v[1]); p.y = pk2(v[2], v[3]);
    p.z = pk2(v[4], v[5]); p.w = pk2(v[6], v[7]);
    *(uint4*)(O + (size_t)g * 8) = p;
}

// ---- 3. merged: blocks [0,625) MFMA GEMM Y = x @ W1 (LDS-staged A);
//  blocks [625,3125) per-row dedupe of buckets (4 rows/block, wave-per-row).
__global__ void k_gy_dedup(const void* A, const unsigned short* Bsw,
                           unsigned char* Yf8, void* Oout, const int* flags,
                           const int* slotcnt, unsigned short* bucket,
                           int* deg_r, int* deg_c) {
    __shared__ unsigned short As[16][264];   // +8 pad: conflict-free b128 reads
    __shared__ int lds[4][BKT];
    __shared__ int cnt[4];
    int b = blockIdx.x;
    int tid = threadIdx.x;
    if (b < 625) {
        // ---- GEMM branch ----
        int r0 = b * 16;
        int af32 = flags[1];
        {
            int row = tid >> 4, seg = tid & 15;
            if (af32) {
                const float* ap = (const float*)A + (size_t)(r0 + row) * HH + seg * 16;
                unsigned short v[16];
                #pragma unroll
                for (int j = 0; j < 16; j += 4) {
                    float4 q = *(const float4*)(ap + j);
                    v[j] = f2bf(q.x); v[j + 1] = f2bf(q.y);
                    v[j + 2] = f2bf(q.z); v[j + 3] = f2bf(q.w);
                }
                uint4 p0, p1;
                p0.x = pk2(v[0], v[1]);  p0.y = pk2(v[2], v[3]);
                p0.z = pk2(v[4], v[5]);  p0.w = pk2(v[6], v[7]);
                p1.x = pk2(v[8], v[9]);  p1.y = pk2(v[10], v[11]);
                p1.z = pk2(v[12], v[13]); p1.w = pk2(v[14], v[15]);
                *(uint4*)&As[row][seg * 16] = p0;
                *(uint4*)&As[row][seg * 16 + 8] = p1;
            } else {
                const unsigned short* ap = (const unsigned short*)A + (size_t)(r0 + row) * HH + seg * 16;
                *(uint4*)&As[row][seg * 16] = *(const uint4*)ap;
                *(uint4*)&As[row][seg * 16 + 8] = *(const uint4*)(ap + 8);
            }
        }
        __syncthreads();
        int wv = tid >> 6;
        int lane = tid & 63;
        int quad = lane >> 4;
        int l16 = lane & 15;
        f32x4 acc[4] = {{0,0,0,0},{0,0,0,0},{0,0,0,0},{0,0,0,0}};
        for (int ks = 0; ks < 8; ks++) {
            bf16x8 af = *(const bf16x8*)&As[l16][ks * 32 + quad * 8];
            #pragma unroll
            for (int t = 0; t < 4; t++) {
                int n = wv * 4 + t;
                bf16x8 bf = *(const bf16x8*)(Bsw + ((size_t)(ks * 16 + n) * 64 + lane) * 8);
                acc[t] = __builtin_amdgcn_mfma_f32_16x16x32_bf16(af, bf, acc[t], 0, 0, 0);
            }
        }
        size_t chunkW = (size_t)NN * HH;
        #pragma unroll
        for (int t = 0; t < 4; t++) {
            int cn = (wv * 4 + t) * 16 + l16;
            #pragma unroll
            for (int r = 0; r < 4; r++) {
                int row = r0 + quad * 4 + r;
                float v = acc[t][r];
                size_t idx = (size_t)row * HH + cn;
                Yf8[idx] = (unsigned char)fp8e(v);
                if (af32) ((float*)Oout)[2 * chunkW + idx] = v;
                else      ((unsigned short*)Oout)[2 * chunkW + idx] = f2bf(v);
            }
        }
        return;
    }
    // ---- dedupe branch: 4 rows, one wave each ----
    int wave = tid >> 6;
    int lane = tid & 63;
    int i = (b - 625) * 4 + wave;
    int d = slotcnt[i];
    if (d > BKT) d = BKT;
    if (lane == 0) cnt[wave] = 0;
    unsigned short* bp = bucket + (size_t)i * BKT;
    for (int t = lane; t < d; t += 64) lds[wave][t] = (int)bp[t];
    __syncthreads();
    for (int t = lane; t < d; t += 64) {
        int c = lds[wave][t];
        int dup = 0;
        for (int u = 0; u < t; u++) dup |= (lds[wave][u] == c);
        if (!dup) {
            int p = atomicAdd(&cnt[wave], 1);
            bp[p] = (unsigned short)c;
            atomicAdd(&deg_c[c], 1);
        }
    }
    __syncthreads();
    if (lane == 0) deg_r[i] = cnt[wave];
}

// ---- 4. dinv2 packed float2
__global__ void k_dinv2(const int* deg_r, const int* deg_c, float* dinv2) {
    int i = blockIdx.x * 256 + threadIdx.x;
    if (i >= NN) return;
    int dr = deg_r[i], dc = deg_c[i];
    dinv2[2 * i]     = dr > 0 ? rsqrtf((float)dr) : 0.0f;
    dinv2[2 * i + 1] = dc > 0 ? rsqrtf((float)dc) : 0.0f;
}

// ---- 5. Fused mid layer: each lane owns 4 feature bytes, decodes ONCE,
//  accumulates into both halves (lap + anorm). Self-term from stash (chunk 2).
__global__ void k_spmm_mid(const unsigned char* Yf8, const void* Oout,
                           const unsigned short* bucket, const int* ucnt,
                           const float* dinv2, const void* bias,
                           const int* flags, unsigned short* H1, unsigned short* H2) {
    int wave = threadIdx.x >> 6;
    int lane = threadIdx.x & 63;
    int fb = lane * 4;
    int i = blockIdx.x * 4 + wave;
    float a1[4] = {0, 0, 0, 0};
    float a2[4] = {0, 0, 0, 0};
    int n = ucnt[i];
    const unsigned short* cp = bucket + (size_t)i * BKT;
    int t = 0;
    for (; t + 4 <= n; t += 4) {
        ushort4 c4 = *(const ushort4*)(cp + t);
        int cx[4] = {(int)c4.x, (int)c4.y, (int)c4.z, (int)c4.w};
        float2 w[4];
        #pragma unroll
        for (int j = 0; j < 4; j++) w[j] = *(const float2*)(dinv2 + 2 * cx[j]);
        unsigned int gv[4];
        #pragma unroll
        for (int j = 0; j < 4; j++)
            gv[j] = *(const unsigned int*)(Yf8 + (size_t)cx[j] * 256 + fb);
        #pragma unroll
        for (int j = 0; j < 4; j++) {
            #pragma unroll
            for (int k = 0; k < 4; k++) {
                float y = fp8d((gv[j] >> (8 * k)) & 0xffu);
                a1[k] += w[j].x * y;
                a2[k] += w[j].y * y;
            }
        }
    }
    for (; t < n; t++) {
        int c = (int)cp[t];
        float2 w = *(const float2*)(dinv2 + 2 * c);
        unsigned int g = *(const unsigned int*)(Yf8 + (size_t)c * 256 + fb);
        #pragma unroll
        for (int k = 0; k < 4; k++) {
            float y = fp8d((g >> (8 * k)) & 0xffu);
            a1[k] += w.x * y;
            a2[k] += w.y * y;
        }
    }
    int f32io = flags[1];
    float bv[4];
    if (f32io) {
        const float* bp = (const float*)bias + fb;
        #pragma unroll
        for (int k = 0; k < 4; k++) bv[k] = bp[k];
    } else {
        uint2 br = *(const uint2*)((const unsigned short*)bias + fb);
        bv[0] = bf2f(br.x & 0xffffu); bv[1] = bf2f(br.x >> 16);
        bv[2] = bf2f(br.y & 0xffffu); bv[3] = bf2f(br.y >> 16);
    }
    float2 wii = *(const float2*)(dinv2 + 2 * i);
    size_t chunkW = (size_t)NN * HH;
    float yv[4];
    if (f32io) {
        const float* sp = (const float*)Oout + 2 * chunkW + (size_t)i * HH + fb;
        #pragma unroll
        for (int k = 0; k < 4; k++) yv[k] = sp[k];
    } else {
        uint2 yi = *(const uint2*)((const unsigned short*)Oout + 2 * chunkW + (size_t)i * HH + fb);
        yv[0] = bf2f(yi.x & 0xffffu); yv[1] = bf2f(yi.x >> 16);
        yv[2] = bf2f(yi.y & 0xffffu); yv[3] = bf2f(yi.y >> 16);
    }
    float h1[4], h2[4];
    #pragma unroll
    for (int k = 0; k < 4; k++) {
        h1[k] = fmaxf(0.f, yv[k] - wii.x * a1[k] + bv[k]);
        h2[k] = fmaxf(0.f, wii.y * a2[k] + bv[k]);
    }
    uint2 p1, p2;
    p1.x = pk2(f2bf(h1[0]), f2bf(h1[1])); p1.y = pk2(f2bf(h1[2]), f2bf(h1[3]));
    p2.x = pk2(f2bf(h2[0]), f2bf(h2[1])); p2.y = pk2(f2bf(h2[2]), f2bf(h2[3]));
    *(uint2*)(H1 + (size_t)i * HH + fb) = p1;
    *(uint2*)(H2 + (size_t)i * HH + fb) = p2;
}

// ---- 6. MFMA GEMM merged (LDS-staged A): [0,625) G1 = H1@W2; [625,1250) G2.
__global__ void k_gg(const unsigned short* H1, const unsigned short* H2,
                     const unsigned short* Bsw, unsigned char* G12f8,
                     void* Oout, const int* flags) {
    __shared__ unsigned short As[16][264];
    int b = blockIdx.x;
    int tid = threadIdx.x;
    int isG1 = (b < 625);
    const unsigned short* A = isG1 ? H1 : H2;
    int r0 = (isG1 ? b : b - 625) * 16;
    {
        int row = tid >> 4, seg = tid & 15;
        const unsigned short* ap = A + (size_t)(r0 + row) * HH + seg * 16;
        *(uint4*)&As[row][seg * 16] = *(const uint4*)ap;
        *(uint4*)&As[row][seg * 16 + 8] = *(const uint4*)(ap + 8);
    }
    __syncthreads();
    int wv = tid >> 6;
    int lane = tid & 63;
    int quad = lane >> 4;
    int l16 = lane & 15;
    f32x4 acc[4] = {{0,0,0,0},{0,0,0,0},{0,0,0,0},{0,0,0,0}};
    for (int ks = 0; ks < 8; ks++) {
        bf16x8 af = *(const bf16x8*)&As[l16][ks * 32 + quad * 8];
        #pragma unroll
        for (int t = 0; t < 4; t++) {
            int n = wv * 4 + t;
            bf16x8 bf = *(const bf16x8*)(Bsw + ((size_t)(ks * 16 + n) * 64 + lane) * 8);
            acc[t] = __builtin_amdgcn_mfma_f32_16x16x32_bf16(af, bf, acc[t], 0, 0, 0);
        }
    }
    size_t chunkW = (size_t)NN * HH;
    int f32io = flags[1];
    #pragma unroll
    for (int t = 0; t < 4; t++) {
        int cn = (wv * 4 + t) * 16 + l16;
        #pragma unroll
        for (int r = 0; r < 4; r++) {
            int row = r0 + quad * 4 + r;
            float v = acc[t][r];
            if (isG1) {
                G12f8[(size_t)row * 512 + cn] = (unsigned char)fp8e(v);
                size_t idx = (size_t)row * HH + cn;
                if (f32io) ((float*)Oout)[chunkW + idx] = v;
                else       ((unsigned short*)Oout)[chunkW + idx] = f2bf(v);
            } else {
                G12f8[(size_t)row * 512 + 256 + cn] = (unsigned char)fp8e(v);
            }
        }
    }
}

// ---- 7. Fused final layer: gather G12_fp8 (512 B/row split across halves);
//  z1 self-term from G1 stash in chunk 1.
__global__ void k_spmm_fin(const unsigned char* G12f8, const unsigned short* bucket,
                           const int* ucnt, const float* dinv2, const void* bias,
                           const int* flags, void* Oout) {
    int wave = threadIdx.x >> 6;
    int lane = threadIdx.x & 63;
    int half = lane >> 5;
    int sub = lane & 31;
    int fb = sub * 8;
    int goff = half * 256 + fb;
    int i = blockIdx.x * 4 + wave;
    float acc[8] = {0, 0, 0, 0, 0, 0, 0, 0};
    int n = ucnt[i];
    const unsigned short* cp = bucket + (size_t)i * BKT;
    int t = 0;
    for (; t + 4 <= n; t += 4) {
        ushort4 c4 = *(const ushort4*)(cp + t);
        int cx[4] = {(int)c4.x, (int)c4.y, (int)c4.z, (int)c4.w};
        float ws[4];
        #pragma unroll
        for (int j = 0; j < 4; j++) {
            float2 w = *(const float2*)(dinv2 + 2 * cx[j]);
            ws[j] = half ? w.y : w.x;
        }
        uint2 gv[4];
        #pragma unroll
        for (int j = 0; j < 4; j++)
            gv[j] = *(const uint2*)(G12f8 + (size_t)cx[j] * 512 + goff);
        #pragma unroll
        for (int j = 0; j < 4; j++) {
            #pragma unroll
            for (int k = 0; k < 4; k++) {
                float y = fp8d((gv[j].x >> (8 * k)) & 0xffu);
                acc[k] += ws[j] * y;
            }
            #pragma unroll
            for (int k = 0; k < 4; k++) {
                float y = fp8d((gv[j].y >> (8 * k)) & 0xffu);
                acc[4 + k] += ws[j] * y;
            }
        }
    }
    for (; t < n; t++) {
        int c = (int)cp[t];
        float2 w = *(const float2*)(dinv2 + 2 * c);
        float wsel = half ? w.y : w.x;
        uint2 g = *(const uint2*)(G12f8 + (size_t)c * 512 + goff);
        #pragma unroll
        for (int k = 0; k < 4; k++) acc[k] += wsel * fp8d((g.x >> (8 * k)) & 0xffu);
        #pragma unroll
        for (int k = 0; k < 4; k++) acc[4 + k] += wsel * fp8d((g.y >> (8 * k)) & 0xffu);
    }
    int f32io = flags[1];
    float bv[8];
    if (f32io) {
        const float* bp = (const float*)bias + fb;
        #pragma unroll
        for (int k = 0; k < 8; k++) bv[k] = bp[k];
    } else {
        uint4 br = *(const uint4*)((const unsigned short*)bias + fb);
        bv[0] = bf2f(br.x & 0xffffu); bv[1] = bf2f(br.x >> 16);
        bv[2] = bf2f(br.y & 0xffffu); bv[3] = bf2f(br.y >> 16);
        bv[4] = bf2f(br.z & 0xffffu); bv[5] = bf2f(br.z >> 16);
        bv[6] = bf2f(br.w & 0xffffu); bv[7] = bf2f(br.w >> 16);
    }
    float2 wii = *(const float2*)(dinv2 + 2 * i);
    size_t base = (size_t)i * HH + fb;
    size_t chunkW = (size_t)NN * HH;
    float z[8];
    if (half == 0) {                                  // z1 = G1[i] - wr_i*sum + b -> chunk 1
        float gvv[8];
        if (f32io) {
            const float* sp = (const float*)Oout + chunkW + base;
            #pragma unroll
            for (int k = 0; k < 8; k++) gvv[k] = sp[k];
        } else {
            uint4 gi = *(const uint4*)((const unsigned short*)Oout + chunkW + base);
            gvv[0] = bf2f(gi.x & 0xffffu); gvv[1] = bf2f(gi.x >> 16);
            gvv[2] = bf2f(gi.y & 0xffffu); gvv[3] = bf2f(gi.y >> 16);
            gvv[4] = bf2f(gi.z & 0xffffu); gvv[5] = bf2f(gi.z >> 16);
            gvv[6] = bf2f(gi.w & 0xffffu); gvv[7] = bf2f(gi.w >> 16);
        }
        #pragma unroll
        for (int k = 0; k < 8; k++) z[k] = gvv[k] - wii.x * acc[k] + bv[k];
        if (f32io) {
            float* o = (float*)Oout + chunkW + base;
            *(float4*)o = make_float4(z[0], z[1], z[2], z[3]);
            *(float4*)(o + 4) = make_float4(z[4], z[5], z[6], z[7]);
        } else {
            uint4 p;
            p.x = pk2(f2bf(z[0]), f2bf(z[1])); p.y = pk2(f2bf(z[2]), f2bf(z[3]));
            p.z = pk2(f2bf(z[4]), f2bf(z[5])); p.w = pk2(f2bf(z[6]), f2bf(z[7]));
            *(uint4*)((unsigned short*)Oout + chunkW + base) = p;
        }
    } else {                                          // z2 = wc_i*sum + b -> chunks 0, 2
        #pragma unroll
        for (int k = 0; k < 8; k++) z[k] = wii.y * acc[k] + bv[k];
        if (f32io) {
            float* o0 = (float*)Oout + base;
            float* o2 = (float*)Oout + 2 * chunkW + base;
            float4 pa = make_float4(z[0], z[1], z[2], z[3]);
            float4 pb = make_float4(z[4], z[5], z[6], z[7]);
            *(float4*)o0 = pa; *(float4*)(o0 + 4) = pb;
            *(float4*)o2 = pa; *(float4*)(o2 + 4) = pb;
        } else {
            uint4 p;
            p.x = pk2(f2bf(z[0]), f2bf(z[1])); p.y = pk2(f2bf(z[2]), f2bf(z[3]));
            p.z = pk2(f2bf(z[4]), f2bf(z[5])); p.w = pk2(f2bf(z[6]), f2bf(z[7]));
            *(uint4*)((unsigned short*)Oout + base) = p;
            *(uint4*)((unsigned short*)Oout + 2 * chunkW + base) = p;
        }
    }
}

extern "C" void kernel_launch(void* const* d_in, const int* in_sizes, int n_in,
                              void* d_out, int out_size, void* d_ws, size_t ws_size,
                              hipStream_t stream) {
    const void* x = 0; const void* ei = 0;
    const void* W1 = 0; const void* b1 = 0; const void* W2 = 0; const void* b2 = 0;
    for (int i = 0; i < n_in; i++) {
        int s = in_sizes[i];
        if (s == NN * HH) x = d_in[i];
        else if (s == 2 * EE) ei = d_in[i];
        else if (s == HH * HH) { if (!W1) W1 = d_in[i]; else W2 = d_in[i]; }
        else if (s == HH) { if (!b1) b1 = d_in[i]; else b2 = d_in[i]; }
    }

    char* ws = (char*)d_ws;
    size_t off = 0;
    int* flags = (int*)(ws + off); off += 256;
    int* slotcnt = (int*)(ws + off); off += (size_t)NN * 4;
    int* deg_c = (int*)(ws + off); off += (size_t)NN * 4;
    int* deg_r = (int*)(ws + off); off += (size_t)NN * 4;
    float* dinv2 = (float*)(ws + off); off += (size_t)NN * 8;
    unsigned short* bucket = (unsigned short*)(ws + off); off += (size_t)NN * BKT * 2;
    unsigned short* W1sw = (unsigned short*)(ws + off); off += (size_t)HH * HH * 2;
    unsigned short* W2sw = (unsigned short*)(ws + off); off += (size_t)HH * HH * 2;
    unsigned char* Yf8 = (unsigned char*)(ws + off); off += (size_t)NN * 256;
    unsigned char* G12f8 = (unsigned char*)(ws + off); off += (size_t)NN * 512;
    unsigned short* H1 = (unsigned short*)(ws + off); off += (size_t)NN * HH * 2;
    unsigned short* H2 = (unsigned short*)(ws + off); off += (size_t)NN * HH * 2;
    // total ~22.22 MB (< proven 22.3 MB)

    // 1. detect + zero counters
    k_init<<<40, 256, 0, stream>>>((const unsigned int*)x, (const unsigned int*)ei,
                                   flags, slotcnt, deg_c);
    // 2. weight swizzle + single-pass edge scatter (replaces count/scan/fill)
    k_prep_scatter<<<64 + EE / 256, 256, 0, stream>>>(W1, W2, ei, flags, W1sw, W2sw,
                                                      slotcnt, bucket);
    // 3. Y = x @ W1 (fp8 table + stash)  ||  per-row dedupe
    k_gy_dedup<<<625 + NN / 4, 256, 0, stream>>>(x, W1sw, Yf8, d_out, flags,
                                                 slotcnt, bucket, deg_r, deg_c);
    // 4. dinv2
    k_dinv2<<<(NN + 255) / 256, 256, 0, stream>>>(deg_r, deg_c, dinv2);
    // 5. fused mid layer (single-decode, dual accumulators)
    k_spmm_mid<<<NN / 4, 256, 0, stream>>>(Yf8, d_out, bucket, deg_r, dinv2, b1,
                                           flags, H1, H2);
    // 6. G GEMMs (fp8 table + G1 stash)
    k_gg<<<1250, 256, 0, stream>>>(H1, H2, W2sw, G12f8, d_out, flags);
    // 7. fused final layer + all three output chunks
    k_spmm_fin<<<NN / 4, 256, 0, stream>>>(G12f8, bucket, deg_r, dinv2, b2, flags, d_out);
}